// Round 4
// baseline (109.368 us; speedup 1.0000x reference)
//
#include <hip/hip_runtime.h>

typedef __attribute__((ext_vector_type(8))) short bf16x8;
typedef __attribute__((ext_vector_type(4))) float f32x4;

#define S_  2048
#define D_  1024
#define H_  16

__device__ __forceinline__ unsigned short f2bf(float x) {
    union { float f; unsigned u; } v; v.f = x;
    unsigned r = v.u + 0x7fffu + ((v.u >> 16) & 1u);
    return (unsigned short)(r >> 16);
}

__device__ __forceinline__ void gload16(const unsigned short* g, unsigned short* l) {
    __builtin_amdgcn_global_load_lds((const __attribute__((address_space(1))) void*)g,
                                     (__attribute__((address_space(3))) void*)l, 16, 0, 0);
}

__device__ __forceinline__ void drain_vm() {
    asm volatile("s_waitcnt vmcnt(0)" ::: "memory");
}

// ---------------- convert f32 -> bf16, 3 tensors fused ----------------
__global__ __launch_bounds__(256) void cvt_f32_bf16(const float* __restrict__ i0,
                                                    const float* __restrict__ i1,
                                                    const float* __restrict__ i2,
                                                    unsigned short* __restrict__ o0,
                                                    unsigned short* __restrict__ o1,
                                                    unsigned short* __restrict__ o2, int n4) {
    int i = blockIdx.x * 256 + threadIdx.x;
    if (i >= n4) return;
    const float* in = blockIdx.y == 0 ? i0 : blockIdx.y == 1 ? i1 : i2;
    unsigned short* out = blockIdx.y == 0 ? o0 : blockIdx.y == 1 ? o1 : o2;
    float4 v = ((const float4*)in)[i];
    ushort4 o;
    o.x = f2bf(v.x); o.y = f2bf(v.y); o.z = f2bf(v.z); o.w = f2bf(v.w);
    ((ushort4*)out)[i] = o;
}

// ---------------- per-head weight transpose f32 -> bf16 ----------------
__global__ void transpose_qkv(const float* __restrict__ Wq, const float* __restrict__ Wk,
                              const float* __restrict__ Wv, unsigned short* __restrict__ Oq,
                              unsigned short* __restrict__ Ok, unsigned short* __restrict__ Ov) {
    __shared__ float t[32][33];
    int which = blockIdx.z >> 4, h = blockIdx.z & 15;
    const float* I = (which == 0 ? Wq : which == 1 ? Wk : Wv) + (long)h * 65536;
    unsigned short* O = (which == 0 ? Oq : which == 1 ? Ok : Ov) + (long)h * 65536;
    int c0 = blockIdx.x * 32, r0 = blockIdx.y * 32;
    t[threadIdx.y][threadIdx.x] = I[(long)(r0 + threadIdx.y) * 64 + c0 + threadIdx.x];
    __syncthreads();
    O[(long)(c0 + threadIdx.y) * 1024 + r0 + threadIdx.x] = f2bf(t[threadIdx.x][threadIdx.y]);
}

__global__ void transpose_wo(const float* __restrict__ in, unsigned short* __restrict__ out) {
    __shared__ float t[32][33];
    int c0 = blockIdx.x * 32, r0 = blockIdx.y * 32;
    t[threadIdx.y][threadIdx.x] = in[(long)(r0 + threadIdx.y) * 1024 + c0 + threadIdx.x];
    __syncthreads();
    out[(long)(c0 + threadIdx.y) * 1024 + r0 + threadIdx.x] = f2bf(t[threadIdx.x][threadIdx.y]);
}

// ---------------- 64x128-tile bf16 MFMA GEMM, 2-phase double-buffered ----------------
// C[m][n] = sum_k A[m][k]*Bt[n][k]; A [M][1024], Bt [N][1024] bf16.
// MODE 0: bf16 C[gm*ldc+gn]; MODE 1: bf16 KEY-PERMUTED transposed store; MODE 2: f32
template<int MODE>
__device__ __forceinline__ void gemm64x128(unsigned short (*As)[64 * 64],
                                           unsigned short (*Bs)[128 * 64],
                                           const unsigned short* __restrict__ A,
                                           const unsigned short* __restrict__ Bt,
                                           void* __restrict__ C, int m0, int n0, int ldc) {
    const int tid = threadIdx.x, wv = tid >> 6, lane = tid & 63, lg = lane >> 4, lr = lane & 15;
    f32x4 acc[4][2] = {};
    const unsigned short* Ab = A + (size_t)m0 * D_;
    const unsigned short* Bb = Bt + (size_t)n0 * D_;
    auto stage = [&](int b, int kt) {
        #pragma unroll
        for (int it = 0; it < 2; ++it) {
            int c = it * 256 + wv * 64 + lane;
            int row = c >> 3, jj = (c & 7) ^ (row & 7);
            gload16(Ab + (size_t)row * D_ + kt * 64 + jj * 8, &As[b][(it * 256 + wv * 64) * 8]);
        }
        #pragma unroll
        for (int it = 0; it < 4; ++it) {
            int c = it * 256 + wv * 64 + lane;
            int row = c >> 3, jj = (c & 7) ^ (row & 7);
            gload16(Bb + (size_t)row * D_ + kt * 64 + jj * 8, &Bs[b][(it * 256 + wv * 64) * 8]);
        }
    };
    stage(0, 0);
    drain_vm();
    __syncthreads();
    int buf = 0;
    for (int kt = 0; kt < 16; ++kt) {
        if (kt + 1 < 16) stage(buf ^ 1, kt + 1);
        #pragma unroll
        for (int kk = 0; kk < 2; ++kk) {
            bf16x8 af[4], bfr[2];
            #pragma unroll
            for (int mf = 0; mf < 4; ++mf) {
                int r = mf * 16 + lr;
                af[mf] = *(const bf16x8*)&As[buf][(r * 8 + ((kk * 4 + lg) ^ (r & 7))) * 8];
            }
            #pragma unroll
            for (int nf = 0; nf < 2; ++nf) {
                int r = wv * 32 + nf * 16 + lr;
                bfr[nf] = *(const bf16x8*)&Bs[buf][(r * 8 + ((kk * 4 + lg) ^ (r & 7))) * 8];
            }
            #pragma unroll
            for (int mf = 0; mf < 4; ++mf)
                #pragma unroll
                for (int nf = 0; nf < 2; ++nf)
                    acc[mf][nf] = __builtin_amdgcn_mfma_f32_16x16x32_bf16(af[mf], bfr[nf], acc[mf][nf], 0, 0, 0);
        }
        drain_vm();
        __syncthreads();
        buf ^= 1;
    }
    #pragma unroll
    for (int mf = 0; mf < 4; ++mf)
        #pragma unroll
        for (int nf = 0; nf < 2; ++nf) {
            if (MODE == 1) {
                // key-permuted transposed store: key gm -> pos m0+(mf>>1)*32+lg*8+(mf&1)*4+j
                int gn = n0 + wv * 32 + nf * 16 + lr;
                int pg = m0 + (mf >> 1) * 32 + lg * 8 + (mf & 1) * 4;
                ushort4 pk;
                pk.x = f2bf(acc[mf][nf][0]); pk.y = f2bf(acc[mf][nf][1]);
                pk.z = f2bf(acc[mf][nf][2]); pk.w = f2bf(acc[mf][nf][3]);
                *(ushort4*)&((unsigned short*)C)[(size_t)gn * ldc + pg] = pk;
            } else {
                #pragma unroll
                for (int j = 0; j < 4; ++j) {
                    int gm = m0 + mf * 16 + lg * 4 + j;
                    int gn = n0 + wv * 32 + nf * 16 + lr;
                    if (MODE == 0) ((unsigned short*)C)[(size_t)gm * ldc + gn] = f2bf(acc[mf][nf][j]);
                    else           ((float*)C)[(size_t)gm * ldc + gn] = acc[mf][nf][j];
                }
            }
        }
}

__global__ __launch_bounds__(256, 3) void proj_kernel(
    const unsigned short* __restrict__ Eq, const unsigned short* __restrict__ Ek,
    const unsigned short* __restrict__ Ev, const unsigned short* __restrict__ Wqt,
    const unsigned short* __restrict__ Wkt, const unsigned short* __restrict__ Wvt,
    unsigned short* __restrict__ Qb, unsigned short* __restrict__ Kb,
    unsigned short* __restrict__ Vtb) {
    __shared__ alignas(16) unsigned short As[2][64 * 64];
    __shared__ alignas(16) unsigned short Bs[2][128 * 64];
    int m0 = blockIdx.x * 64, n0 = blockIdx.y * 128;
    if (blockIdx.z == 0)      gemm64x128<0>(As, Bs, Eq, Wqt, Qb, m0, n0, 1024);
    else if (blockIdx.z == 1) gemm64x128<0>(As, Bs, Ek, Wkt, Kb, m0, n0, 1024);
    else                      gemm64x128<1>(As, Bs, Ev, Wvt, Vtb, m0, n0, S_);
}

__global__ __launch_bounds__(256, 3) void out_gemm(const unsigned short* __restrict__ Cat,
                                                   const unsigned short* __restrict__ Wot,
                                                   float* __restrict__ Out) {
    __shared__ alignas(16) unsigned short As[2][64 * 64];
    __shared__ alignas(16) unsigned short Bs[2][128 * 64];
    gemm64x128<2>(As, Bs, Cat, Wot, Out, blockIdx.x * 64, blockIdx.y * 128, 1024);
}

// ---------------- flash attention, split-KV x2, exp2-domain softmax ----------------
// grid (S/64, H, 2), 256 thr; wave w owns q rows [s0+16w,+16); lane's q = lr
__global__ __launch_bounds__(256, 4) void attn_kernel(
    const unsigned short* __restrict__ Qb, const unsigned short* __restrict__ Kb,
    const unsigned short* __restrict__ Vtb, float* __restrict__ Op, float* __restrict__ Ml) {
    __shared__ alignas(16) unsigned short Ks[2][64 * 64];
    __shared__ alignas(16) unsigned short Vs[2][64 * 64];

    const int h = blockIdx.y, s0 = blockIdx.x * 64, half = blockIdx.z;
    const int tid = threadIdx.x, wv = tid >> 6, lane = tid & 63, lg = lane >> 4, lr = lane & 15;

    const unsigned short* qrow = Qb + (size_t)(s0 + wv * 16 + lr) * D_ + h * 64;
    const bf16x8 q0 = *(const bf16x8*)(qrow + lg * 8);
    const bf16x8 q1 = *(const bf16x8*)(qrow + 32 + lg * 8);

    float m_run = 0.f, l_run = 0.f;   // 0 = max-floor (exact; avoids -inf paths)
    f32x4 o_acc[4] = {};

    const unsigned short* KhB = Kb + h * 64;
    const unsigned short* VhB = Vtb + (size_t)(h * 64) * S_;  // key-permuted [64 dv][S]

    auto stage = [&](int b, int t) {
        #pragma unroll
        for (int it = 0; it < 2; ++it) {
            int c = it * 256 + wv * 64 + lane;
            int row = c >> 3, jj = (c & 7) ^ (row & 7);
            gload16(KhB + (size_t)(t * 64 + row) * D_ + jj * 8, &Ks[b][(it * 256 + wv * 64) * 8]);
        }
        #pragma unroll
        for (int it = 0; it < 2; ++it) {
            int c = it * 256 + wv * 64 + lane;
            int row = c >> 3, jj = (c & 7) ^ (row & 7);
            gload16(VhB + (size_t)row * S_ + t * 64 + jj * 8, &Vs[b][(it * 256 + wv * 64) * 8]);
        }
    };

    const int t0 = half * 16;
    stage(0, t0);
    drain_vm();
    __syncthreads();
    int buf = 0;
    for (int tt = 0; tt < 16; ++tt) {
        if (tt + 1 < 16) stage(buf ^ 1, t0 + tt + 1);
        const unsigned short* K_ = Ks[buf];
        const unsigned short* V_ = Vs[buf];

        // S^T tile: sc[n] layout: key = n*16 + lg*4 + j, q = lr
        f32x4 sc[4] = {};
        __builtin_amdgcn_s_setprio(1);
        #pragma unroll
        for (int kk = 0; kk < 2; ++kk) {
            bf16x8 q = kk ? q1 : q0;
            #pragma unroll
            for (int n = 0; n < 4; ++n) {
                int r = n * 16 + lr;
                bf16x8 kf = *(const bf16x8*)&K_[(r * 8 + ((kk * 4 + lg) ^ (r & 7))) * 8];
                sc[n] = __builtin_amdgcn_mfma_f32_16x16x32_bf16(kf, q, sc[n], 0, 0, 0);
            }
        }
        __builtin_amdgcn_s_setprio(0);

        float mx = 0.f;
        #pragma unroll
        for (int n = 0; n < 4; ++n) {
            sc[n] *= 0.18033688011f;  // (1/8) * log2(e)
            mx = fmaxf(mx, fmaxf(fmaxf(sc[n][0], sc[n][1]), fmaxf(sc[n][2], sc[n][3])));
        }
        mx = fmaxf(mx, __shfl_xor(mx, 16));
        mx = fmaxf(mx, __shfl_xor(mx, 32));
        float mn = fmaxf(m_run, mx);
        float alpha = exp2f(m_run - mn);
        m_run = mn;
        float rs = 0.f;
        #pragma unroll
        for (int n = 0; n < 4; ++n)
            #pragma unroll
            for (int j = 0; j < 4; ++j) {
                float p = exp2f(sc[n][j] - mn);
                sc[n][j] = p;
                rs += p;
            }
        rs += __shfl_xor(rs, 16);
        rs += __shfl_xor(rs, 32);
        l_run = l_run * alpha + rs;
        #pragma unroll
        for (int n = 0; n < 4; ++n) o_acc[n] *= alpha;

        // P as PV B-frag, lane-local under k-slot perm pi(lg*8+i)=lg*4+(i&3)+16*(i>>2)
        bf16x8 pB[2];
        #pragma unroll
        for (int kk = 0; kk < 2; ++kk) {
            bf16x8 pb;
            #pragma unroll
            for (int i = 0; i < 4; ++i) pb[i] = (short)f2bf(sc[2 * kk][i]);
            #pragma unroll
            for (int i = 0; i < 4; ++i) pb[4 + i] = (short)f2bf(sc[2 * kk + 1][i]);
            pB[kk] = pb;
        }
        // O^T += V^T(perm) * P^T : V stored key-permuted, one 16B read per fragment
        __builtin_amdgcn_s_setprio(1);
        #pragma unroll
        for (int n = 0; n < 4; ++n) {
            int r = n * 16 + lr;
            #pragma unroll
            for (int kk = 0; kk < 2; ++kk) {
                bf16x8 vf = *(const bf16x8*)&V_[(r * 8 + ((kk * 4 + lg) ^ (r & 7))) * 8];
                o_acc[n] = __builtin_amdgcn_mfma_f32_16x16x32_bf16(vf, pB[kk], o_acc[n], 0, 0, 0);
            }
        }
        __builtin_amdgcn_s_setprio(0);
        drain_vm();
        __syncthreads();
        buf ^= 1;
    }
    size_t q = s0 + wv * 16 + lr;
    size_t base = ((size_t)(half * 16 + h) * S_ + q) * 64;
    #pragma unroll
    for (int n = 0; n < 4; ++n)
        *(f32x4*)&Op[base + n * 16 + lg * 4] = o_acc[n];
    if (lg == 0) {
        size_t mi = (size_t)(half * 16 + h) * S_ + q;
        Ml[mi * 2] = m_run;
        Ml[mi * 2 + 1] = l_run;
    }
}

// ---------------- combine the 2 KV-halves ----------------
__global__ __launch_bounds__(256) void combine(const float* __restrict__ Op,
                                               const float* __restrict__ Ml,
                                               unsigned short* __restrict__ Cat) {
    int gid = blockIdx.x * 256 + threadIdx.x;          // 16(d4) * 2048(s) * 16(h)
    int d4 = gid & 15, s = (gid >> 4) & 2047, h = gid >> 15;
    size_t i0 = (size_t)h * S_ + s, i1 = (size_t)(16 + h) * S_ + s;
    float m0 = Ml[i0 * 2], l0 = Ml[i0 * 2 + 1];
    float m1 = Ml[i1 * 2], l1 = Ml[i1 * 2 + 1];
    float M = fmaxf(m0, m1);
    float w0 = exp2f(m0 - M), w1 = exp2f(m1 - M);
    float inv = 1.f / fmaxf(w0 * l0 + w1 * l1, 1e-30f);
    f32x4 a = *(const f32x4*)&Op[i0 * 64 + d4 * 4];
    f32x4 b = *(const f32x4*)&Op[i1 * 64 + d4 * 4];
    ushort4 pk;
    pk.x = f2bf((w0 * a[0] + w1 * b[0]) * inv);
    pk.y = f2bf((w0 * a[1] + w1 * b[1]) * inv);
    pk.z = f2bf((w0 * a[2] + w1 * b[2]) * inv);
    pk.w = f2bf((w0 * a[3] + w1 * b[3]) * inv);
    *(ushort4*)&Cat[(size_t)s * D_ + h * 64 + d4 * 4] = pk;
}

extern "C" void kernel_launch(void* const* d_in, const int* in_sizes, int n_in,
                              void* d_out, int out_size, void* d_ws, size_t ws_size,
                              hipStream_t stream) {
    const float* enc_q = (const float*)d_in[0];
    const float* enc_k = (const float*)d_in[1];
    const float* enc_v = (const float*)d_in[2];
    const float* W_q   = (const float*)d_in[3];
    const float* W_k   = (const float*)d_in[4];
    const float* W_v   = (const float*)d_in[5];
    const float* W_out = (const float*)d_in[6];
    float* out = (float*)d_out;

    const size_t M1 = 1024 * 1024;
    unsigned short* Eqb = (unsigned short*)d_ws;   // [S][D] bf16 (dead after proj)
    unsigned short* Ekb = Eqb + 2 * M1;
    unsigned short* Evb = Ekb + 2 * M1;
    unsigned short* Wqt = Evb + 2 * M1;            // [H*DK][D] (dead after proj)
    unsigned short* Wkt = Wqt + M1;
    unsigned short* Wvt = Wkt + M1;
    unsigned short* Wot = Wvt + M1;                // [D][H*DV] (kept for out_gemm)
    unsigned short* Qb  = Wot + M1;                // [S][H*DK]
    unsigned short* Kb  = Qb  + 2 * M1;            // [S][H*DK]
    unsigned short* Vtb = Kb  + 2 * M1;            // [H*DV][S] key-permuted
    unsigned short* Cat = Vtb + 2 * M1;            // [S][H*DV]
    // f32 partials overlap the post-proj dead region [Eqb .. Wvt): 18 MiB
    float* Op = (float*)d_ws;                               // 32*2048*64 f32 = 16 MiB
    float* Ml = (float*)((char*)d_ws + 16u * 1024 * 1024);  // 32*2048*2 f32 = 0.5 MiB

    cvt_f32_bf16<<<dim3(2048, 3), 256, 0, stream>>>(enc_q, enc_k, enc_v, Eqb, Ekb, Evb, 524288);
    dim3 tb(32, 32);
    transpose_qkv<<<dim3(2, 32, 48), tb, 0, stream>>>(W_q, W_k, W_v, Wqt, Wkt, Wvt);
    transpose_wo<<<dim3(32, 32), tb, 0, stream>>>(W_out, Wot);
    proj_kernel<<<dim3(32, 8, 3), 256, 0, stream>>>(Eqb, Ekb, Evb, Wqt, Wkt, Wvt, Qb, Kb, Vtb);
    attn_kernel<<<dim3(32, 16, 2), 256, 0, stream>>>(Qb, Kb, Vtb, Op, Ml);
    combine<<<2048, 256, 0, stream>>>(Op, Ml, Cat);
    out_gemm<<<dim3(32, 8), 256, 0, stream>>>(Cat, Wot, out);
}